// Round 5
// baseline (123.165 us; speedup 1.0000x reference)
//
#include <hip/hip_runtime.h>
#include <hip/hip_bf16.h>
#include <stdint.h>

// ---------------------------------------------------------------------------
// GroundingLoss fused pipeline, R5.
// R4 -> R5: epilogue VALU surgery. Pipe accounting at R4: MFMA 13.6us (fixed),
// VALU issue 20.6us (dominant!), stalls ~40%. The softmax epilogue had
// 16-deep SERIAL float chains (compiler can't reassociate w/o fast-math).
// Now: exp2-domain softmax (c*log2e once, exp2(t-m)), pairwise depth-4
// reduction trees for max/se/swe, rcp instead of div.
// Structure unchanged: fragment-major bf16 ws, no LDS, wave = 2a x 2b tiles,
// grid 4096, 4 waves/SIMD.
// ---------------------------------------------------------------------------

typedef __attribute__((ext_vector_type(8))) short short8;    // 8 bf16 = 16B
typedef __attribute__((ext_vector_type(16))) float float16;  // 32x32 acc

#define NTOK 256
#define KDIM 256
#define LOG2E 1.44269504088896f

__device__ __forceinline__ unsigned short f2bf(float f) {
    unsigned int u = __float_as_uint(f);
    unsigned int r = (u + 0x7fffu + ((u >> 16) & 1u)) >> 16;  // RNE
    return (unsigned short)r;
}

__device__ __forceinline__ short8 cvt8(const float* p) {
    float4 f0 = ((const float4*)p)[0];
    float4 f1 = ((const float4*)p)[1];
    short8 v;
    v[0] = (short)f2bf(f0.x); v[1] = (short)f2bf(f0.y);
    v[2] = (short)f2bf(f0.z); v[3] = (short)f2bf(f0.w);
    v[4] = (short)f2bf(f1.x); v[5] = (short)f2bf(f1.y);
    v[6] = (short)f2bf(f1.z); v[7] = (short)f2bf(f1.w);
    return v;
}

// fp32 -> bf16 fragment-major: unit(g, ks, half, l31) = g*1024 + ks*64 + half*32 + l31.
__global__ void conv_kernel(const float* __restrict__ x,
                            const float* __restrict__ z,
                            short8* __restrict__ outbf,
                            float* __restrict__ out0) {
    const int uid = blockIdx.x * 256 + threadIdx.x;
    if (uid == 0) out0[0] = 0.0f;   // loss accumulator (loss_part atomicAdds)
    const int u = uid & 262143;
    const float* src = (uid < 262144) ? x : z;
    const int g  = u >> 10;
    const int r  = u & 1023;
    const int ks = r >> 6;
    const int h  = (r >> 5) & 1;
    const int l  = r & 31;
    outbf[uid] = cvt8(src + ((g * 32 + l) * KDIM + ks * 16 + h * 8));
}

// grid = 4096 (64 a-groups x 64 b-groups of 4), 256 threads, 4 waves/SIMD.
template <bool F32SRC>
__global__ __launch_bounds__(256, 4)
void sim_kernel(const short8* __restrict__ xbf, const short8* __restrict__ zbf,
                const float* __restrict__ xf, const float* __restrict__ zf,
                float* __restrict__ S) {
    const int tid  = threadIdx.x;
    const int lane = tid & 63;
    const int wid  = tid >> 6;
    const int aw   = wid >> 1;
    const int bw   = wid & 1;
    const int l31  = lane & 31;
    const int half = lane >> 5;
    const int bid  = blockIdx.x;
    const int a0   = (bid >> 6) * 4;
    const int b0   = (bid & 63) * 4;

    const int ag = a0 + 2 * aw;
    const int bg = b0 + 2 * bw;

    const short8* pa = xbf + ag * 1024 + lane;
    const short8* pb = zbf + bg * 1024 + lane;

    const float* fa = xf + ((ag * 32 + l31) * KDIM + half * 8);
    const float* fb = zf + ((bg * 32 + l31) * KDIM + half * 8);

    float16 acc[2][2];
#pragma unroll
    for (int ai = 0; ai < 2; ai++)
#pragma unroll
        for (int bi = 0; bi < 2; bi++)
#pragma unroll
            for (int r = 0; r < 16; r++) acc[ai][bi][r] = 0.0f;

#pragma unroll 4
    for (int ks = 0; ks < 16; ks++) {
        short8 a0f, a1f, b0f, b1f;
        if (F32SRC) {
            a0f = cvt8(fa + ks * 16);
            a1f = cvt8(fa + 32 * KDIM + ks * 16);
            b0f = cvt8(fb + ks * 16);
            b1f = cvt8(fb + 32 * KDIM + ks * 16);
        } else {
            const int off = ks * 64;
            a0f = pa[off];
            a1f = pa[off + 1024];
            b0f = pb[off];
            b1f = pb[off + 1024];
        }
        acc[0][0] = __builtin_amdgcn_mfma_f32_32x32x16_bf16(a0f, b0f, acc[0][0], 0, 0, 0);
        acc[0][1] = __builtin_amdgcn_mfma_f32_32x32x16_bf16(a0f, b1f, acc[0][1], 0, 0, 0);
        acc[1][0] = __builtin_amdgcn_mfma_f32_32x32x16_bf16(a1f, b0f, acc[1][0], 0, 0, 0);
        acc[1][1] = __builtin_amdgcn_mfma_f32_32x32x16_bf16(a1f, b1f, acc[1][1], 0, 0, 0);
    }

    // Epilogue, exp2-domain softmax with depth-4 trees.
    // C-layout: col = lane&31; column j lives in lanes j and j+32 (16 regs each).
#pragma unroll
    for (int ai = 0; ai < 2; ai++) {
#pragma unroll
        for (int bi = 0; bi < 2; bi++) {
            float16 c = acc[ai][bi];
            float t[16];
#pragma unroll
            for (int r = 0; r < 16; r++) t[r] = c[r] * LOG2E;

            // max tree (depth 4)
            float m8[8], m4[4], m2[2];
#pragma unroll
            for (int r = 0; r < 8; r++) m8[r] = fmaxf(t[2 * r], t[2 * r + 1]);
#pragma unroll
            for (int r = 0; r < 4; r++) m4[r] = fmaxf(m8[2 * r], m8[2 * r + 1]);
            m2[0] = fmaxf(m4[0], m4[1]); m2[1] = fmaxf(m4[2], m4[3]);
            float m = fmaxf(m2[0], m2[1]);
            m = fmaxf(m, __shfl_xor(m, 32, 64));

            // e = 2^(t - m)
            float e[16];
#pragma unroll
            for (int r = 0; r < 16; r++) e[r] = exp2f(t[r] - m);

            // se tree (depth 4)
            float s8[8], s4[4], s2[2];
#pragma unroll
            for (int r = 0; r < 8; r++) s8[r] = e[2 * r] + e[2 * r + 1];
#pragma unroll
            for (int r = 0; r < 4; r++) s4[r] = s8[2 * r] + s8[2 * r + 1];
            s2[0] = s4[0] + s4[1]; s2[1] = s4[2] + s4[3];
            float se = s2[0] + s2[1];

            // swe: 8 mul + 8 fma + 7-add tree
            float w8[8], w4[4], w2[2];
#pragma unroll
            for (int r = 0; r < 8; r++) {
                float p = e[2 * r] * c[2 * r];
                w8[r] = fmaf(e[2 * r + 1], c[2 * r + 1], p);
            }
#pragma unroll
            for (int r = 0; r < 4; r++) w4[r] = w8[2 * r] + w8[2 * r + 1];
            w2[0] = w4[0] + w4[1]; w2[1] = w4[2] + w4[3];
            float swe = w2[0] + w2[1];

            se  += __shfl_xor(se, 32, 64);
            swe += __shfl_xor(swe, 32, 64);
            float cv = swe * __builtin_amdgcn_rcpf(se);
            // all-reduce over 32 columns (values identical in both halves)
#pragma unroll
            for (int off = 1; off < 32; off <<= 1) cv += __shfl_xor(cv, off, 64);
            if (lane == 0)
                S[(ag + ai) * NTOK + (bg + bi)] = cv * (1.0f / 32.0f);
        }
    }
}

// 64 blocks x 256 threads; wave w handles n = bid*4 + w. One atomicAdd/block.
__global__ void loss_part(const float* __restrict__ S, float* __restrict__ out) {
    const int lane = threadIdx.x & 63;
    const int wid  = threadIdx.x >> 6;
    const int n    = blockIdx.x * 4 + wid;

    float cv[4], rv[4];
#pragma unroll
    for (int k = 0; k < 4; k++) {
        const int t = lane + 64 * k;
        cv[k] = S[t * NTOK + n];
        rv[k] = S[n * NTOK + t];
    }
    float m = fmaxf(fmaxf(cv[0], cv[1]), fmaxf(cv[2], cv[3]));
#pragma unroll
    for (int off = 1; off < 64; off <<= 1) m = fmaxf(m, __shfl_xor(m, off, 64));
    float s = 0.0f;
#pragma unroll
    for (int k = 0; k < 4; k++) s += __expf(cv[k] - m);
#pragma unroll
    for (int off = 1; off < 64; off <<= 1) s += __shfl_xor(s, off, 64);
    float lse_col = m + __logf(s);

    float m2 = fmaxf(fmaxf(rv[0], rv[1]), fmaxf(rv[2], rv[3]));
#pragma unroll
    for (int off = 1; off < 64; off <<= 1) m2 = fmaxf(m2, __shfl_xor(m2, off, 64));
    float s2 = 0.0f;
#pragma unroll
    for (int k = 0; k < 4; k++) s2 += __expf(rv[k] - m2);
#pragma unroll
    for (int off = 1; off < 64; off <<= 1) s2 += __shfl_xor(s2, off, 64);
    float lse_row = m2 + __logf(s2);

    __shared__ float red[4];
    if (lane == 0) {
        float diag = S[n * NTOK + n];
        red[wid] = (lse_col - diag) + (lse_row - diag);
    }
    __syncthreads();
    if (threadIdx.x == 0)
        atomicAdd(out, (red[0] + red[1] + red[2] + red[3]) * (1.0f / 256.0f));
}

__global__ void zero_kernel(float* __restrict__ out) {
    out[0] = 0.0f;
}

extern "C" void kernel_launch(void* const* d_in, const int* in_sizes, int n_in,
                              void* d_out, int out_size, void* d_ws, size_t ws_size,
                              hipStream_t stream) {
    const float* x = (const float*)d_in[0];   // [256,32,256]
    const float* z = (const float*)d_in[1];   // [256,32,256]
    float* out = (float*)d_out;

    const size_t bf_bytes = 524288ull * 16ull;         // 8 MB fragment-major
    const size_t s_bytes  = 256ull * 256ull * 4ull;    // 256 KB

    if (ws_size >= bf_bytes + s_bytes) {
        short8* xbf = (short8*)d_ws;          // 262144 units
        short8* zbf = xbf + 262144;
        float*  S   = (float*)((char*)d_ws + bf_bytes);
        conv_kernel<<<2048, 256, 0, stream>>>(x, z, (short8*)d_ws, out);
        sim_kernel<false><<<4096, 256, 0, stream>>>(xbf, zbf, nullptr, nullptr, S);
        loss_part<<<64, 256, 0, stream>>>(S, out);
    } else {
        float* S = (float*)d_ws;              // 256 KB
        zero_kernel<<<1, 1, 0, stream>>>(out);
        sim_kernel<true><<<4096, 256, 0, stream>>>(nullptr, nullptr, x, z, S);
        loss_part<<<64, 256, 0, stream>>>(S, out);
    }
}

// Round 6
// 118.232 us; speedup vs baseline: 1.0417x; 1.0417x over previous
//
#include <hip/hip_runtime.h>
#include <hip/hip_bf16.h>
#include <stdint.h>

// ---------------------------------------------------------------------------
// GroundingLoss fused pipeline, R6.
// R2-R5 all ~56-60us: invariant was FRAGMENT TRAFFIC, not occupancy/LDS.
// 2x2 wave tile -> 1 GB fragment traffic -> 27us L1-port time (> 13.6us MFMA
// floor); pipes barely overlap -> ~60us. R6: A-RESIDENT wave: each wave keeps
// its 2 a-group K-stripes in registers (32 x short8 = 128 VGPR, loaded once),
// loops 16 b-groups: 16 B-frag loads -> 32 MFMAs each. Traffic 576 MB ->
// L1 ~15us ~= MFMA 13.6us. Block = 4 waves sharing b-slice (B hits L1).
// 512 blocks, 2 waves/SIMD. Epilogue: __expf + depth-4 trees (R5's exp2f
// regressed: OCML fixup code).
// ---------------------------------------------------------------------------

typedef __attribute__((ext_vector_type(8))) short short8;    // 8 bf16 = 16B
typedef __attribute__((ext_vector_type(16))) float float16;  // 32x32 acc

#define NTOK 256
#define KDIM 256

__device__ __forceinline__ unsigned short f2bf(float f) {
    unsigned int u = __float_as_uint(f);
    unsigned int r = (u + 0x7fffu + ((u >> 16) & 1u)) >> 16;  // RNE
    return (unsigned short)r;
}

__device__ __forceinline__ short8 cvt8(const float* p) {
    float4 f0 = ((const float4*)p)[0];
    float4 f1 = ((const float4*)p)[1];
    short8 v;
    v[0] = (short)f2bf(f0.x); v[1] = (short)f2bf(f0.y);
    v[2] = (short)f2bf(f0.z); v[3] = (short)f2bf(f0.w);
    v[4] = (short)f2bf(f1.x); v[5] = (short)f2bf(f1.y);
    v[6] = (short)f2bf(f1.z); v[7] = (short)f2bf(f1.w);
    return v;
}

// fp32 -> bf16 fragment-major: unit(g, ks, half, l31) = g*1024 + ks*64 + half*32 + l31.
__global__ void conv_kernel(const float* __restrict__ x,
                            const float* __restrict__ z,
                            short8* __restrict__ outbf,
                            float* __restrict__ out0) {
    const int uid = blockIdx.x * 256 + threadIdx.x;
    if (uid == 0) out0[0] = 0.0f;   // loss accumulator (loss_part atomicAdds)
    const int u = uid & 262143;
    const float* src = (uid < 262144) ? x : z;
    const int g  = u >> 10;
    const int r  = u & 1023;
    const int ks = r >> 6;
    const int h  = (r >> 5) & 1;
    const int l  = r & 31;
    outbf[uid] = cvt8(src + ((g * 32 + l) * KDIM + ks * 16 + h * 8));
}

// Softmax-weighted column mean of one 32x32 C-tile, store to S[a*NTOK+b].
__device__ __forceinline__ void tile_epilogue(const float16& c, float* S,
                                              int a, int b, int lane) {
    // max tree (depth 4) over the 16 regs, then cross-half
    float m8[8], m4[4];
#pragma unroll
    for (int r = 0; r < 8; r++) m8[r] = fmaxf(c[2 * r], c[2 * r + 1]);
#pragma unroll
    for (int r = 0; r < 4; r++) m4[r] = fmaxf(m8[2 * r], m8[2 * r + 1]);
    float m = fmaxf(fmaxf(m4[0], m4[1]), fmaxf(m4[2], m4[3]));
    m = fmaxf(m, __shfl_xor(m, 32, 64));

    float e[16];
#pragma unroll
    for (int r = 0; r < 16; r++) e[r] = __expf(c[r] - m);

    float s8[8], s4[4];
#pragma unroll
    for (int r = 0; r < 8; r++) s8[r] = e[2 * r] + e[2 * r + 1];
#pragma unroll
    for (int r = 0; r < 4; r++) s4[r] = s8[2 * r] + s8[2 * r + 1];
    float se = (s4[0] + s4[1]) + (s4[2] + s4[3]);

    float w8[8], w4[4];
#pragma unroll
    for (int r = 0; r < 8; r++)
        w8[r] = fmaf(e[2 * r + 1], c[2 * r + 1], e[2 * r] * c[2 * r]);
#pragma unroll
    for (int r = 0; r < 4; r++) w4[r] = w8[2 * r] + w8[2 * r + 1];
    float swe = (w4[0] + w4[1]) + (w4[2] + w4[3]);

    se  += __shfl_xor(se, 32, 64);
    swe += __shfl_xor(swe, 32, 64);
    float cv = swe * __builtin_amdgcn_rcpf(se);
#pragma unroll
    for (int off = 1; off < 32; off <<= 1) cv += __shfl_xor(cv, off, 64);
    if (lane == 0) S[a * NTOK + b] = cv * (1.0f / 32.0f);
}

// 512 blocks x 256 threads, 2 waves/SIMD. Wave w of block bid:
//   a-pair = (bid>>4)*4 + w  (a-groups 2p, 2p+1), b-slice = (bid&15)*16..+15.
// A K-stripes (2 x 16 frags) resident in VGPRs; per b-group: 16 B loads -> 32 MFMAs.
template <bool F32SRC>
__global__ __launch_bounds__(256, 2)
void sim_kernel(const short8* __restrict__ xbf, const short8* __restrict__ zbf,
                const float* __restrict__ xf, const float* __restrict__ zf,
                float* __restrict__ S) {
    const int tid  = threadIdx.x;
    const int lane = tid & 63;
    const int wid  = tid >> 6;
    const int l31  = lane & 31;
    const int half = lane >> 5;
    const int bid  = blockIdx.x;

    const int ap  = (bid >> 4) * 4 + wid;   // a-pair 0..127
    const int ag0 = ap * 2;
    const int ag1 = ap * 2 + 1;
    const int bg0 = (bid & 15) * 16;        // first b-group of slice

    short8 A0[16], A1[16];
    if (F32SRC) {
        const float* fa0 = xf + ((ag0 * 32 + l31) * KDIM + half * 8);
        const float* fa1 = xf + ((ag1 * 32 + l31) * KDIM + half * 8);
#pragma unroll
        for (int k = 0; k < 16; k++) {
            A0[k] = cvt8(fa0 + k * 16);
            A1[k] = cvt8(fa1 + k * 16);
        }
    } else {
        const short8* pa = xbf + ag0 * 1024 + lane;
#pragma unroll
        for (int k = 0; k < 16; k++) {
            A0[k] = pa[k * 64];
            A1[k] = pa[1024 + k * 64];
        }
    }

#pragma unroll 1
    for (int bi = 0; bi < 16; bi++) {
        const int bg = bg0 + bi;
        short8 B[16];
        if (F32SRC) {
            const float* fb = zf + ((bg * 32 + l31) * KDIM + half * 8);
#pragma unroll
            for (int k = 0; k < 16; k++) B[k] = cvt8(fb + k * 16);
        } else {
            const short8* pb = zbf + bg * 1024 + lane;
#pragma unroll
            for (int k = 0; k < 16; k++) B[k] = pb[k * 64];
        }

        float16 acc0, acc1;
#pragma unroll
        for (int r = 0; r < 16; r++) { acc0[r] = 0.0f; acc1[r] = 0.0f; }
#pragma unroll
        for (int k = 0; k < 16; k++) {
            acc0 = __builtin_amdgcn_mfma_f32_32x32x16_bf16(A0[k], B[k], acc0, 0, 0, 0);
            acc1 = __builtin_amdgcn_mfma_f32_32x32x16_bf16(A1[k], B[k], acc1, 0, 0, 0);
        }

        tile_epilogue(acc0, S, ag0, bg, lane);
        tile_epilogue(acc1, S, ag1, bg, lane);
    }
}

// 64 blocks x 256 threads; wave w handles n = bid*4 + w. One atomicAdd/block.
__global__ void loss_part(const float* __restrict__ S, float* __restrict__ out) {
    const int lane = threadIdx.x & 63;
    const int wid  = threadIdx.x >> 6;
    const int n    = blockIdx.x * 4 + wid;

    float cv[4], rv[4];
#pragma unroll
    for (int k = 0; k < 4; k++) {
        const int t = lane + 64 * k;
        cv[k] = S[t * NTOK + n];
        rv[k] = S[n * NTOK + t];
    }
    float m = fmaxf(fmaxf(cv[0], cv[1]), fmaxf(cv[2], cv[3]));
#pragma unroll
    for (int off = 1; off < 64; off <<= 1) m = fmaxf(m, __shfl_xor(m, off, 64));
    float s = 0.0f;
#pragma unroll
    for (int k = 0; k < 4; k++) s += __expf(cv[k] - m);
#pragma unroll
    for (int off = 1; off < 64; off <<= 1) s += __shfl_xor(s, off, 64);
    float lse_col = m + __logf(s);

    float m2 = fmaxf(fmaxf(rv[0], rv[1]), fmaxf(rv[2], rv[3]));
#pragma unroll
    for (int off = 1; off < 64; off <<= 1) m2 = fmaxf(m2, __shfl_xor(m2, off, 64));
    float s2 = 0.0f;
#pragma unroll
    for (int k = 0; k < 4; k++) s2 += __expf(rv[k] - m2);
#pragma unroll
    for (int off = 1; off < 64; off <<= 1) s2 += __shfl_xor(s2, off, 64);
    float lse_row = m2 + __logf(s2);

    __shared__ float red[4];
    if (lane == 0) {
        float diag = S[n * NTOK + n];
        red[wid] = (lse_col - diag) + (lse_row - diag);
    }
    __syncthreads();
    if (threadIdx.x == 0)
        atomicAdd(out, (red[0] + red[1] + red[2] + red[3]) * (1.0f / 256.0f));
}

__global__ void zero_kernel(float* __restrict__ out) {
    out[0] = 0.0f;
}

extern "C" void kernel_launch(void* const* d_in, const int* in_sizes, int n_in,
                              void* d_out, int out_size, void* d_ws, size_t ws_size,
                              hipStream_t stream) {
    const float* x = (const float*)d_in[0];   // [256,32,256]
    const float* z = (const float*)d_in[1];   // [256,32,256]
    float* out = (float*)d_out;

    const size_t bf_bytes = 524288ull * 16ull;         // 8 MB fragment-major
    const size_t s_bytes  = 256ull * 256ull * 4ull;    // 256 KB

    if (ws_size >= bf_bytes + s_bytes) {
        short8* xbf = (short8*)d_ws;          // 262144 units
        short8* zbf = xbf + 262144;
        float*  S   = (float*)((char*)d_ws + bf_bytes);
        conv_kernel<<<2048, 256, 0, stream>>>(x, z, (short8*)d_ws, out);
        sim_kernel<false><<<512, 256, 0, stream>>>(xbf, zbf, nullptr, nullptr, S);
        loss_part<<<64, 256, 0, stream>>>(S, out);
    } else {
        float* S = (float*)d_ws;              // 256 KB
        zero_kernel<<<1, 1, 0, stream>>>(out);
        sim_kernel<true><<<512, 256, 0, stream>>>(nullptr, nullptr, x, z, S);
        loss_part<<<64, 256, 0, stream>>>(S, out);
    }
}

// Round 7
// 113.543 us; speedup vs baseline: 1.0847x; 1.0413x over previous
//
#include <hip/hip_runtime.h>
#include <hip/hip_bf16.h>
#include <stdint.h>

// ---------------------------------------------------------------------------
// GroundingLoss fused pipeline, R7.
// R2-R6 invariant solved: L1/vector-mem PORT (64 B/cyc/CU, consumed on hits
// AND misses) was the binding resource (R6 VGPR=104 proved the compiler
// rematerialized the "resident" A loads -> 1.5 GB port traffic -> 39us).
// R7: (a) A fragments made compiler-opaque via empty asm -> truly resident
// (128 VGPR); (b) B staged block-cooperatively into double-buffered LDS via
// global_load_lds width=16 (fragment reads move to the separate LDS pipe);
// (c) prefetch next b-group before computing current (m97 structure).
// Per-CU: global port ~3us, LDS ~12.7us, MFMA 13.8us (floor), VALU ~8us.
// ---------------------------------------------------------------------------

typedef __attribute__((ext_vector_type(8))) short short8;    // 8 bf16 = 16B
typedef __attribute__((ext_vector_type(16))) float float16;  // 32x32 acc

typedef const __attribute__((address_space(1))) unsigned int* gptr_as1;
typedef __attribute__((address_space(3))) unsigned int* lptr_as3;

#define NTOK 256
#define KDIM 256

__device__ __forceinline__ unsigned short f2bf(float f) {
    unsigned int u = __float_as_uint(f);
    unsigned int r = (u + 0x7fffu + ((u >> 16) & 1u)) >> 16;  // RNE
    return (unsigned short)r;
}

__device__ __forceinline__ short8 cvt8(const float* p) {
    float4 f0 = ((const float4*)p)[0];
    float4 f1 = ((const float4*)p)[1];
    short8 v;
    v[0] = (short)f2bf(f0.x); v[1] = (short)f2bf(f0.y);
    v[2] = (short)f2bf(f0.z); v[3] = (short)f2bf(f0.w);
    v[4] = (short)f2bf(f1.x); v[5] = (short)f2bf(f1.y);
    v[6] = (short)f2bf(f1.z); v[7] = (short)f2bf(f1.w);
    return v;
}

// fp32 -> bf16 fragment-major: unit(g, ks, half, l31) = g*1024 + ks*64 + half*32 + l31.
__global__ void conv_kernel(const float* __restrict__ x,
                            const float* __restrict__ z,
                            short8* __restrict__ outbf,
                            float* __restrict__ out0) {
    const int uid = blockIdx.x * 256 + threadIdx.x;
    if (uid == 0) out0[0] = 0.0f;   // loss accumulator (loss_part atomicAdds)
    const int u = uid & 262143;
    const float* src = (uid < 262144) ? x : z;
    const int g  = u >> 10;
    const int r  = u & 1023;
    const int ks = r >> 6;
    const int h  = (r >> 5) & 1;
    const int l  = r & 31;
    outbf[uid] = cvt8(src + ((g * 32 + l) * KDIM + ks * 16 + h * 8));
}

// Softmax-weighted column mean of one 32x32 C-tile, store to S[a*NTOK+b].
__device__ __forceinline__ void tile_epilogue(const float16& c, float* S,
                                              int a, int b, int lane) {
    float m8[8], m4[4];
#pragma unroll
    for (int r = 0; r < 8; r++) m8[r] = fmaxf(c[2 * r], c[2 * r + 1]);
#pragma unroll
    for (int r = 0; r < 4; r++) m4[r] = fmaxf(m8[2 * r], m8[2 * r + 1]);
    float m = fmaxf(fmaxf(m4[0], m4[1]), fmaxf(m4[2], m4[3]));
    m = fmaxf(m, __shfl_xor(m, 32, 64));

    float e[16];
#pragma unroll
    for (int r = 0; r < 16; r++) e[r] = __expf(c[r] - m);

    float s8[8], s4[4];
#pragma unroll
    for (int r = 0; r < 8; r++) s8[r] = e[2 * r] + e[2 * r + 1];
#pragma unroll
    for (int r = 0; r < 4; r++) s4[r] = s8[2 * r] + s8[2 * r + 1];
    float se = (s4[0] + s4[1]) + (s4[2] + s4[3]);

    float w8[8], w4[4];
#pragma unroll
    for (int r = 0; r < 8; r++)
        w8[r] = fmaf(e[2 * r + 1], c[2 * r + 1], e[2 * r] * c[2 * r]);
#pragma unroll
    for (int r = 0; r < 4; r++) w4[r] = w8[2 * r] + w8[2 * r + 1];
    float swe = (w4[0] + w4[1]) + (w4[2] + w4[3]);

    se  += __shfl_xor(se, 32, 64);
    swe += __shfl_xor(swe, 32, 64);
    float cv = swe * __builtin_amdgcn_rcpf(se);
#pragma unroll
    for (int off = 1; off < 32; off <<= 1) cv += __shfl_xor(cv, off, 64);
    if (lane == 0) S[a * NTOK + b] = cv * (1.0f / 32.0f);
}

// 512 blocks x 256 threads, 2 blocks/CU. Wave w: a-pair (bid>>4)*4+w,
// block b-slice = (bid&15)*16 .. +15. A resident in VGPRs (asm-pinned);
// B double-buffered in LDS via global_load_lds(16B).
template <bool F32SRC>
__global__ __launch_bounds__(256, 2)
void sim_kernel(const short8* __restrict__ xbf, const short8* __restrict__ zbf,
                const float* __restrict__ xf, const float* __restrict__ zf,
                float* __restrict__ S) {
    __shared__ short8 smem[2048];   // 2 buffers x 1024 units (16 KB each)

    const int tid  = threadIdx.x;
    const int lane = tid & 63;
    const int wid  = tid >> 6;
    const int l31  = lane & 31;
    const int half = lane >> 5;
    const int bid  = blockIdx.x;

    const int ap  = (bid >> 4) * 4 + wid;   // a-pair 0..127
    const int ag0 = ap * 2;
    const int ag1 = ap * 2 + 1;
    const int bg0 = (bid & 15) * 16;        // first b-group of slice

    // ---- A fragments: load once, pin in VGPRs (asm makes them opaque) ----
    short8 A0[16], A1[16];
    if (F32SRC) {
        const float* fa0 = xf + ((ag0 * 32 + l31) * KDIM + half * 8);
        const float* fa1 = xf + ((ag1 * 32 + l31) * KDIM + half * 8);
#pragma unroll
        for (int k = 0; k < 16; k++) {
            A0[k] = cvt8(fa0 + k * 16);
            A1[k] = cvt8(fa1 + k * 16);
        }
    } else {
        const short8* pa = xbf + ag0 * 1024 + lane;
#pragma unroll
        for (int k = 0; k < 16; k++) {
            A0[k] = pa[k * 64];
            A1[k] = pa[1024 + k * 64];
        }
    }
#pragma unroll
    for (int k = 0; k < 16; k++) {
        asm volatile("" : "+v"(A0[k]));
        asm volatile("" : "+v"(A1[k]));
    }

    if (F32SRC) {
        // Fallback: direct global reads + in-flight convert (no LDS).
#pragma unroll 1
        for (int bi = 0; bi < 16; bi++) {
            const int bg = bg0 + bi;
            const float* fb = zf + ((bg * 32 + l31) * KDIM + half * 8);
            float16 acc0, acc1;
#pragma unroll
            for (int r = 0; r < 16; r++) { acc0[r] = 0.0f; acc1[r] = 0.0f; }
#pragma unroll
            for (int k = 0; k < 16; k++) {
                short8 B = cvt8(fb + k * 16);
                acc0 = __builtin_amdgcn_mfma_f32_32x32x16_bf16(A0[k], B, acc0, 0, 0, 0);
                acc1 = __builtin_amdgcn_mfma_f32_32x32x16_bf16(A1[k], B, acc1, 0, 0, 0);
            }
            tile_epilogue(acc0, S, ag0, bg, lane);
            tile_epilogue(acc1, S, ag1, bg, lane);
        }
        return;
    }

    // ---- staging helper: 16 KB (one b-group, fragment-contiguous) ----
    // wave w stages units [w*256 .. w*256+255]: 4 calls x 64 lanes x 16B.
    const short8* zsl = zbf + (size_t)bg0 * 1024;
#define STAGE(buf, bi)                                                        \
    {                                                                         \
        const short8* gsrc = zsl + (bi) * 1024 + wid * 256 + lane;            \
        short8* ldst = &smem[(buf) * 1024 + wid * 256];                       \
        __builtin_amdgcn_global_load_lds((gptr_as1)(gsrc),       (lptr_as3)(ldst),       16, 0, 0); \
        __builtin_amdgcn_global_load_lds((gptr_as1)(gsrc + 64),  (lptr_as3)(ldst + 64),  16, 0, 0); \
        __builtin_amdgcn_global_load_lds((gptr_as1)(gsrc + 128), (lptr_as3)(ldst + 128), 16, 0, 0); \
        __builtin_amdgcn_global_load_lds((gptr_as1)(gsrc + 192), (lptr_as3)(ldst + 192), 16, 0, 0); \
    }

    STAGE(0, 0);
    __syncthreads();

#pragma unroll 1
    for (int bi = 0; bi < 16; bi++) {
        const int cur = bi & 1;
        if (bi + 1 < 16) STAGE(1 - cur, bi + 1);   // prefetch next b-group

        const short8* lb = &smem[cur * 1024];
        float16 acc0, acc1;
#pragma unroll
        for (int r = 0; r < 16; r++) { acc0[r] = 0.0f; acc1[r] = 0.0f; }
#pragma unroll
        for (int k = 0; k < 16; k++) {
            short8 B = lb[k * 64 + lane];
            acc0 = __builtin_amdgcn_mfma_f32_32x32x16_bf16(A0[k], B, acc0, 0, 0, 0);
            acc1 = __builtin_amdgcn_mfma_f32_32x32x16_bf16(A1[k], B, acc1, 0, 0, 0);
        }

        const int bg = bg0 + bi;
        tile_epilogue(acc0, S, ag0, bg, lane);
        tile_epilogue(acc1, S, ag1, bg, lane);

        __syncthreads();   // all waves done with buf[cur]; drains prefetch too
    }
#undef STAGE
}

// 64 blocks x 256 threads; wave w handles n = bid*4 + w. One atomicAdd/block.
__global__ void loss_part(const float* __restrict__ S, float* __restrict__ out) {
    const int lane = threadIdx.x & 63;
    const int wid  = threadIdx.x >> 6;
    const int n    = blockIdx.x * 4 + wid;

    float cv[4], rv[4];
#pragma unroll
    for (int k = 0; k < 4; k++) {
        const int t = lane + 64 * k;
        cv[k] = S[t * NTOK + n];
        rv[k] = S[n * NTOK + t];
    }
    float m = fmaxf(fmaxf(cv[0], cv[1]), fmaxf(cv[2], cv[3]));
#pragma unroll
    for (int off = 1; off < 64; off <<= 1) m = fmaxf(m, __shfl_xor(m, off, 64));
    float s = 0.0f;
#pragma unroll
    for (int k = 0; k < 4; k++) s += __expf(cv[k] - m);
#pragma unroll
    for (int off = 1; off < 64; off <<= 1) s += __shfl_xor(s, off, 64);
    float lse_col = m + __logf(s);

    float m2 = fmaxf(fmaxf(rv[0], rv[1]), fmaxf(rv[2], rv[3]));
#pragma unroll
    for (int off = 1; off < 64; off <<= 1) m2 = fmaxf(m2, __shfl_xor(m2, off, 64));
    float s2 = 0.0f;
#pragma unroll
    for (int k = 0; k < 4; k++) s2 += __expf(rv[k] - m2);
#pragma unroll
    for (int off = 1; off < 64; off <<= 1) s2 += __shfl_xor(s2, off, 64);
    float lse_row = m2 + __logf(s2);

    __shared__ float red[4];
    if (lane == 0) {
        float diag = S[n * NTOK + n];
        red[wid] = (lse_col - diag) + (lse_row - diag);
    }
    __syncthreads();
    if (threadIdx.x == 0)
        atomicAdd(out, (red[0] + red[1] + red[2] + red[3]) * (1.0f / 256.0f));
}

__global__ void zero_kernel(float* __restrict__ out) {
    out[0] = 0.0f;
}

extern "C" void kernel_launch(void* const* d_in, const int* in_sizes, int n_in,
                              void* d_out, int out_size, void* d_ws, size_t ws_size,
                              hipStream_t stream) {
    const float* x = (const float*)d_in[0];   // [256,32,256]
    const float* z = (const float*)d_in[1];   // [256,32,256]
    float* out = (float*)d_out;

    const size_t bf_bytes = 524288ull * 16ull;         // 8 MB fragment-major
    const size_t s_bytes  = 256ull * 256ull * 4ull;    // 256 KB

    if (ws_size >= bf_bytes + s_bytes) {
        short8* xbf = (short8*)d_ws;          // 262144 units
        short8* zbf = xbf + 262144;
        float*  S   = (float*)((char*)d_ws + bf_bytes);
        conv_kernel<<<2048, 256, 0, stream>>>(x, z, (short8*)d_ws, out);
        sim_kernel<false><<<512, 256, 0, stream>>>(xbf, zbf, nullptr, nullptr, S);
        loss_part<<<64, 256, 0, stream>>>(S, out);
    } else {
        float* S = (float*)d_ws;              // 256 KB
        zero_kernel<<<1, 1, 0, stream>>>(out);
        sim_kernel<true><<<512, 256, 0, stream>>>(nullptr, nullptr, x, z, S);
        loss_part<<<64, 256, 0, stream>>>(S, out);
    }
}